// Round 4
// baseline (440.606 us; speedup 1.0000x reference)
//
#include <hip/hip_runtime.h>
#include <hip/hip_cooperative_groups.h>
#include <hip/hip_bf16.h>
#include <math.h>

namespace cg = cooperative_groups;

// GAT layer, V=8192, E=262144, D=128.
// out[i] = (S + sum_{distinct edges (i,j)} (exp(a_ij)-1)*hw[j]) / (V + sum (exp(a_ij)-1))
// a_ij = leakyrelu(s1[i]+s2[j], 0.2), s1=hw@att[:128], s2=hw@att[128:], S=colsum(hw).
//
// R3 -> R4: per-kernel tweaks were neutral; total-minus-fill (~76us) >> modeled
// kernel time (~22us) => inter-dispatch overhead dominates. Collapse memset +
// 3 kernels into ONE cooperative kernel with grid.sync() phases. W transposed
// to global Wt in phase 0 (no 68KB LDS tile -> keeps 4 blocks/CU residency);
// phase 1 k-splits across waves (W L1 traffic /4); colsum via per-block
// partials Pb reduced by 8 blocks in phase 2 (no same-line atomic storm).

#define V 8192
#define E 262144
#define D 128
#define NEG_SLOPE 0.2f
#define CAP 96     // bucket capacity/row; max expected degree ~55 for E/V=32
#define NB 1024    // grid blocks = 4 blocks/CU * 256 CU (exact co-residency)

// ---------------- Phase 0: transpose W -> Wt, zero cnt and S ----------------
__device__ __forceinline__ void phase_init(const float* __restrict__ W,
                                           float* __restrict__ Wt,
                                           int* __restrict__ cnt,
                                           float* __restrict__ S) {
    int g = blockIdx.x * 256 + threadIdx.x;          // 0 .. 262143
    if (g < D * D) {
        int o = g >> 7, k = g & 127;
        Wt[k * D + o] = W[g];                        // coalesced read, scattered write (64KB)
    } else if (g < D * D + V) {
        cnt[g - D * D] = 0;
    } else if (g < D * D + V + D) {
        S[g - D * D - V] = 0.f;
    }
}

// ---------------- Phase 1: hw = h @ W^T, fused s1/s2 + colsum partials ------
// 8 rows/block. Each wave owns a 32-wide k-slice; lane owns 2 cols. Cross-wave
// reduce through 16KB LDS. W traffic per CU = 16 waves * 16KB = 256KB (L1/L2).
__device__ __forceinline__ void phase_hw(const float* __restrict__ h,
                                         const float* __restrict__ Wt,
                                         const float* __restrict__ att,
                                         float* __restrict__ hw,
                                         float* __restrict__ s1,
                                         float* __restrict__ s2,
                                         float* __restrict__ Pb,
                                         float* scr) {
    int r0 = blockIdx.x * 8;
    int wv = threadIdx.x >> 6;        // 0..3 -> k-slice
    int lane = threadIdx.x & 63;
    int c2 = lane * 2;                // 2 cols per lane
    int ks = wv * 32;
    float2 acc[8];
    #pragma unroll
    for (int r = 0; r < 8; ++r) acc[r] = make_float2(0.f, 0.f);
    #pragma unroll 2
    for (int kc = 0; kc < 32; kc += 4) {
        int k = ks + kc;
        float2 w0 = *(const float2*)&Wt[(k + 0) * D + c2];   // coalesced 512B/inst
        float2 w1 = *(const float2*)&Wt[(k + 1) * D + c2];
        float2 w2 = *(const float2*)&Wt[(k + 2) * D + c2];
        float2 w3 = *(const float2*)&Wt[(k + 3) * D + c2];
        #pragma unroll
        for (int r = 0; r < 8; ++r) {
            float4 hv = *(const float4*)&h[(r0 + r) * D + k];  // wave-uniform broadcast
            acc[r].x += hv.x * w0.x + hv.y * w1.x + hv.z * w2.x + hv.w * w3.x;
            acc[r].y += hv.x * w0.y + hv.y * w1.y + hv.z * w2.y + hv.w * w3.y;
        }
    }
    #pragma unroll
    for (int r = 0; r < 8; ++r)
        *(float2*)&scr[(wv * 8 + r) * D + c2] = acc[r];
    __syncthreads();
    // reduce 4 k-slices: thread (rq, c4) owns row rq, cols c4..c4+3
    int rq = threadIdx.x >> 5;
    int c4 = (threadIdx.x & 31) * 4;
    float4 v = make_float4(0.f, 0.f, 0.f, 0.f);
    #pragma unroll
    for (int w = 0; w < 4; ++w) {
        float4 p = *(const float4*)&scr[(w * 8 + rq) * D + c4];
        v.x += p.x; v.y += p.y; v.z += p.z; v.w += p.w;
    }
    int row = r0 + rq;
    *(float4*)&hw[row * D + c4] = v;
    // fused s1/s2 (32-lane group reduce)
    float4 a1 = *(const float4*)&att[c4];
    float4 a2 = *(const float4*)&att[D + c4];
    float p1 = v.x * a1.x + v.y * a1.y + v.z * a1.z + v.w * a1.w;
    float p2 = v.x * a2.x + v.y * a2.y + v.z * a2.z + v.w * a2.w;
    #pragma unroll
    for (int m = 16; m; m >>= 1) { p1 += __shfl_xor(p1, m); p2 += __shfl_xor(p2, m); }
    if ((threadIdx.x & 31) == 0) { s1[row] = p1; s2[row] = p2; }
    // colsum partial for this block -> Pb[block][col] (plain stores, no atomics)
    __syncthreads();
    *(float4*)&scr[rq * D + c4] = v;
    __syncthreads();
    if (rq == 0) {
        float4 t = make_float4(0.f, 0.f, 0.f, 0.f);
        #pragma unroll
        for (int r = 0; r < 8; ++r) {
            float4 p = *(const float4*)&scr[r * D + c4];
            t.x += p.x; t.y += p.y; t.z += p.z; t.w += p.w;
        }
        *(float4*)&Pb[blockIdx.x * D + c4] = t;
    }
}

// ---------------- Phase 2: scatter edges; blocks 0..7 reduce Pb -> S --------
__device__ __forceinline__ void phase_scatter(const int* __restrict__ ei,
                                              const float* __restrict__ s1,
                                              const float* __restrict__ s2,
                                              int* __restrict__ cnt,
                                              int2* __restrict__ bucket,
                                              const float* __restrict__ Pb,
                                              float* __restrict__ S,
                                              float* scr) {
    int e = blockIdx.x * 256 + threadIdx.x;          // exactly E threads
    int src = ei[e];
    int dst = ei[E + e];
    float a = s1[src] + s2[dst];
    a = a > 0.f ? a : NEG_SLOPE * a;
    float w = expf(a) - 1.f;
    int pos = atomicAdd(&cnt[src], 1);
    if (pos < CAP)
        bucket[src * CAP + pos] = make_int2(dst, __float_as_int(w));
    if (blockIdx.x < 8) {                            // S reduction (128 rows of Pb each)
        int c = threadIdx.x & 127;
        int rh = threadIdx.x >> 7;                   // 0/1
        float t = 0.f;
        int rbase = blockIdx.x * (NB / 8);
        for (int r = rh; r < NB / 8; r += 2)
            t += Pb[(rbase + r) * D + c];
        scr[threadIdx.x] = t;
        __syncthreads();
        if (threadIdx.x < D)
            atomicAdd(&S[c], scr[c] + scr[D + c]);   // 8*128 atomics total
    }
}

// ---------------- Phase 3: per-row gather + dedup + epilogue (2 rows/wave) --
__device__ __forceinline__ void phase_row(const int2* __restrict__ bucket,
                                          const int* __restrict__ cnt,
                                          const float* __restrict__ hw,
                                          const float* __restrict__ S,
                                          float* __restrict__ out) {
    int gw = (blockIdx.x * 256 + threadIdx.x) >> 6;  // 0..4095
    int lane = threadIdx.x & 63;
    float2 s = *(const float2*)&S[lane * 2];
    for (int rr = 0; rr < 2; ++rr) {
        int row = gw * 2 + rr;
        int deg = cnt[row];
        if (deg > CAP) deg = CAP;
        const int2* b = bucket + row * CAP;
        int2 e0 = b[lane];
        int2 e1 = (lane < CAP - 64) ? b[64 + lane] : make_int2(-1, 0);
        int   d0 = (lane < deg)      ? e0.x : -1;
        float w0 = (lane < deg)      ? __int_as_float(e0.y) : 0.f;
        int   d1 = (64 + lane < deg) ? e1.x : -1;
        float w1 = (64 + lane < deg) ? __int_as_float(e1.y) : 0.f;
        int n0 = deg < 64 ? deg : 64;
        // branch-free dedup: zero weight of later duplicates (scores identical)
        bool dup0 = false, dup1 = false;
        for (int j = 0; j < n0; ++j) {
            int dj = __shfl(d0, j);
            dup0 |= (d0 == dj) & (lane > j);
            dup1 |= (d1 == dj);
        }
        for (int j = 64; j < deg; ++j) {
            int dj = __shfl(d1, j - 64);
            dup1 |= (d1 == dj) & (lane > j - 64);
        }
        if (dup0) w0 = 0.f;
        if (dup1) w1 = 0.f;
        float2 acc = make_float2(0.f, 0.f);
        float dex = 0.f;
        for (int j = 0; j < n0; ++j) {
            int   dj = __shfl(d0, j);
            float wj = __shfl(w0, j);
            float2 hv = *(const float2*)&hw[dj * D + lane * 2];
            acc.x += wj * hv.x; acc.y += wj * hv.y;
            dex += wj;
        }
        for (int j = 64; j < deg; ++j) {
            int   dj = __shfl(d1, j - 64);
            float wj = __shfl(w1, j - 64);
            float2 hv = *(const float2*)&hw[dj * D + lane * 2];
            acc.x += wj * hv.x; acc.y += wj * hv.y;
            dex += wj;
        }
        float inv = 1.f / ((float)V + dex);
        float2 o;
        o.x = (s.x + acc.x) * inv;
        o.y = (s.y + acc.y) * inv;
        *(float2*)&out[row * D + lane * 2] = o;
    }
}

// ---------------- monolithic cooperative kernel -----------------------------
__global__ __launch_bounds__(256, 4) void k_gat_coop(
        const float* __restrict__ h, const int* __restrict__ ei,
        const float* __restrict__ W, const float* __restrict__ att,
        float* __restrict__ hw, float* __restrict__ s1, float* __restrict__ s2,
        float* __restrict__ S, int* __restrict__ cnt, int2* __restrict__ bucket,
        float* __restrict__ Wt, float* __restrict__ Pb, float* __restrict__ out) {
    __shared__ float scr[4 * 8 * D];   // 16KB
    cg::grid_group g = cg::this_grid();
    phase_init(W, Wt, cnt, S);
    g.sync();
    phase_hw(h, Wt, att, hw, s1, s2, Pb, scr);
    g.sync();
    phase_scatter(ei, s1, s2, cnt, bucket, Pb, S, scr);
    g.sync();
    phase_row(bucket, cnt, hw, S, out);
}

// ---------------- fallback: same phases as 4 plain kernels ------------------
__global__ __launch_bounds__(256, 4) void k_init_f(const float* W, float* Wt, int* cnt, float* S) {
    phase_init(W, Wt, cnt, S);
}
__global__ __launch_bounds__(256, 4) void k_hw_f(const float* h, const float* Wt, const float* att,
        float* hw, float* s1, float* s2, float* Pb) {
    __shared__ float scr[4 * 8 * D];
    phase_hw(h, Wt, att, hw, s1, s2, Pb, scr);
}
__global__ __launch_bounds__(256, 4) void k_sc_f(const int* ei, const float* s1, const float* s2,
        int* cnt, int2* bucket, const float* Pb, float* S) {
    __shared__ float scr[4 * 8 * D];
    phase_scatter(ei, s1, s2, cnt, bucket, Pb, S, scr);
}
__global__ __launch_bounds__(256, 4) void k_row_f(const int2* bucket, const int* cnt,
        const float* hw, const float* S, float* out) {
    phase_row(bucket, cnt, hw, S, out);
}

extern "C" void kernel_launch(void* const* d_in, const int* in_sizes, int n_in,
                              void* d_out, int out_size, void* d_ws, size_t ws_size,
                              hipStream_t stream) {
    const float* h   = (const float*)d_in[0];
    const int*   ei  = (const int*)d_in[1];
    const float* W   = (const float*)d_in[2];
    const float* att = (const float*)d_in[3];
    float* out = (float*)d_out;

    char* ws = (char*)d_ws;
    // workspace layout (bytes):
    //   hw     @ 0           4,194,304
    //   s1     @ 4,194,304      32,768
    //   s2     @ 4,227,072      32,768
    //   S      @ 4,259,840         512
    //   cnt    @ 4,260,352      32,768
    //   bucket @ 4,293,120   6,291,456   (8192 * 96 * 8B)
    //   Wt     @ 10,584,576     65,536   (W transposed, [k][o])
    //   Pb     @ 10,650,112    524,288   (per-block colsum partials [NB][D])
    float* hw  = (float*)(ws);
    float* s1  = (float*)(ws + 4194304);
    float* s2  = (float*)(ws + 4227072);
    float* S   = (float*)(ws + 4259840);
    int*   cnt = (int*)(ws + 4260352);
    int2*  bucket = (int2*)(ws + 4293120);
    float* Wt  = (float*)(ws + 10584576);
    float* Pb  = (float*)(ws + 10650112);

    void* args[] = {(void*)&h, (void*)&ei, (void*)&W, (void*)&att, (void*)&hw,
                    (void*)&s1, (void*)&s2, (void*)&S, (void*)&cnt, (void*)&bucket,
                    (void*)&Wt, (void*)&Pb, (void*)&out};
    hipError_t err = hipLaunchCooperativeKernel((const void*)k_gat_coop,
                                                dim3(NB), dim3(256), args, 0, stream);
    if (err != hipSuccess) {
        // cooperative path unavailable (e.g. capture restriction): same phases
        // as 4 plain dispatches (kernel boundaries provide the grid sync).
        k_init_f<<<NB, 256, 0, stream>>>(W, Wt, cnt, S);
        k_hw_f  <<<NB, 256, 0, stream>>>(h, Wt, att, hw, s1, s2, Pb);
        k_sc_f  <<<NB, 256, 0, stream>>>(ei, s1, s2, cnt, bucket, Pb, S);
        k_row_f <<<NB, 256, 0, stream>>>(bucket, cnt, hw, S, out);
    }
}

// Round 5
// 130.711 us; speedup vs baseline: 3.3708x; 3.3708x over previous
//
#include <hip/hip_runtime.h>
#include <hip/hip_bf16.h>
#include <math.h>

// GAT layer, V=8192, E=262144, D=128.
// out[i] = (S + sum_{distinct (i,j)} (exp(a_ij)-1)*hw[j]) / (V + sum (exp(a_ij)-1))
// a_ij = leakyrelu(s1[i]+s2[j], 0.2).  Identities used:
//   s1 = h @ (W^T att1), s2 = h @ (W^T att2), S = W @ colsum(h)
// so s1/s2/S never touch hw -> scatter + GEMM become independent (same dispatch).
//
// R4 -> R5: coop grid.sync measured ~115us each (379us kernel, VALUBusy 2.7%)
// -> back to 3 plain dispatches. Fixed R3's hidden costs: S atomic hotspot
// (65K same-line atomics) -> plain-store partials Pc; GEMM reads Wt from L2
// (no 67KB LDS tile / ds_read_b128 bottleneck); k_row dedup fused into gather
// via ballot (1 ds op/entry); scatter at 1 edge/thread (4096 waves).

#define V 8192
#define E 262144
#define D 128
#define NEG_SLOPE 0.2f
#define CAP 96    // bucket capacity/row; max expected degree ~55 (11-sigma safe)

// ---------------- K_A: cnt=0, Wt, u1/u2, s1/s2, colsum(h) partials ----------
// 256 blocks x 256 threads; 32 h-rows per block.
__global__ __launch_bounds__(256) void k_pre(const float* __restrict__ h,
                                             const float* __restrict__ W,
                                             const float* __restrict__ att,
                                             float* __restrict__ Wt,
                                             float* __restrict__ s1,
                                             float* __restrict__ s2,
                                             float* __restrict__ Pc,
                                             int* __restrict__ cnt) {
    __shared__ float atts[2 * D];
    __shared__ float us[2 * D];      // u1 | u2
    __shared__ float csc[4][D];      // per-wave colsum partials
    int t = threadIdx.x, b = blockIdx.x;
    atts[t] = att[t];
    if (t < 32) cnt[b * 32 + t] = 0;             // zero cnt, no memset dispatch
    if (b < 64) {                                 // transpose W -> Wt (64KB)
        int g = b * 256 + t;
        Wt[(g & 127) * D + (g >> 7)] = W[g];
    }
    __syncthreads();
    if (t < D) {                                  // u1/u2 = W^T att (per block)
        float u1 = 0.f, u2 = 0.f;
        #pragma unroll 4
        for (int o = 0; o < D; ++o) {
            float wv = W[o * D + t];              // coalesced 512B/iter, L2-hot
            u1 += wv * atts[o];
            u2 += wv * atts[D + o];
        }
        us[t] = u1; us[D + t] = u2;
    }
    __syncthreads();
    int wv = t >> 6, lane = t & 63;
    float2 u1v = *(const float2*)&us[lane * 2];
    float2 u2v = *(const float2*)&us[D + lane * 2];
    int r0 = b * 32 + wv * 8;
    float cx = 0.f, cy = 0.f;
    for (int r = 0; r < 8; ++r) {
        float2 hv = *(const float2*)&h[(r0 + r) * D + lane * 2];
        cx += hv.x; cy += hv.y;
        float p1 = hv.x * u1v.x + hv.y * u1v.y;
        float p2 = hv.x * u2v.x + hv.y * u2v.y;
        #pragma unroll
        for (int m = 32; m; m >>= 1) { p1 += __shfl_xor(p1, m); p2 += __shfl_xor(p2, m); }
        if (lane == 0) { s1[r0 + r] = p1; s2[r0 + r] = p2; }
    }
    *(float2*)&csc[wv][lane * 2] = make_float2(cx, cy);
    __syncthreads();
    if (t < D)                                    // plain-store partials (no atomics)
        Pc[b * D + t] = csc[0][t] + csc[1][t] + csc[2][t] + csc[3][t];
}

// ---------------- K_B: scatter (b<1024) | S-finalize (b==1024) | GEMM -------
// grid = 1024 + 1 + 512 = 1537 blocks x 256 threads.
__global__ __launch_bounds__(256) void k_mid(const float* __restrict__ h,
                                             const float* __restrict__ Wt,
                                             const float* __restrict__ W,
                                             const int* __restrict__ ei,
                                             const float* __restrict__ s1,
                                             const float* __restrict__ s2,
                                             const float* __restrict__ Pc,
                                             float* __restrict__ hw,
                                             float* __restrict__ S,
                                             int* __restrict__ cnt,
                                             int2* __restrict__ bucket) {
    __shared__ float scr[4 * 16 * D];   // 32KB: GEMM k-slice reduce; S-block reuses
    int b = blockIdx.x, t = threadIdx.x;
    if (b < 1024) {
        // scatter: 1 edge/thread, 4096 waves -> atomic latency hidden
        int g = b * 256 + t;
        int src = ei[g];
        int dst = ei[E + g];
        float a = s1[src] + s2[dst];
        a = a > 0.f ? a : NEG_SLOPE * a;
        float w = expf(a) - 1.f;
        int pos = atomicAdd(&cnt[src], 1);
        if (pos < CAP)
            bucket[src * CAP + pos] = make_int2(dst, __float_as_int(w));
    } else if (b == 1024) {
        // c = reduce Pc (256 partials); S = W @ c
        if (t < D) {
            float c = 0.f;
            #pragma unroll 4
            for (int bb = 0; bb < 256; ++bb) c += Pc[bb * D + t];   // coalesced
            scr[t] = c;
        }
        __syncthreads();
        if (t < D) {
            float acc = 0.f;
            #pragma unroll
            for (int k = 0; k < D; k += 4) {
                float4 wv = *(const float4*)&W[t * D + k];   // thread streams own row (L2)
                float4 cv = *(const float4*)&scr[k];
                acc += wv.x * cv.x + wv.y * cv.y + wv.z * cv.z + wv.w * cv.w;
            }
            S[t] = acc;
        }
    } else {
        // GEMM hw = h @ W^T: 16 rows/block; wave owns 32-k slice, lane owns 2 cols.
        // Wt read straight from L2 (coalesced float2), h via wave-uniform float4.
        int r0 = (b - 1025) * 16;
        int wv = t >> 6, lane = t & 63;
        int c2 = lane * 2, ks = wv * 32;
        float2 acc[16];
        #pragma unroll
        for (int r = 0; r < 16; ++r) acc[r] = make_float2(0.f, 0.f);
        for (int kc = 0; kc < 32; kc += 4) {
            int k = ks + kc;
            float2 w0 = *(const float2*)&Wt[(k + 0) * D + c2];
            float2 w1 = *(const float2*)&Wt[(k + 1) * D + c2];
            float2 w2 = *(const float2*)&Wt[(k + 2) * D + c2];
            float2 w3 = *(const float2*)&Wt[(k + 3) * D + c2];
            #pragma unroll
            for (int r = 0; r < 16; ++r) {
                float4 hv = *(const float4*)&h[(r0 + r) * D + k];  // uniform broadcast
                acc[r].x += hv.x * w0.x + hv.y * w1.x + hv.z * w2.x + hv.w * w3.x;
                acc[r].y += hv.x * w0.y + hv.y * w1.y + hv.z * w2.y + hv.w * w3.y;
            }
        }
        #pragma unroll
        for (int r = 0; r < 16; ++r)
            *(float2*)&scr[(wv * 16 + r) * D + c2] = acc[r];
        __syncthreads();
        // reduce 4 k-slices; thread -> row t>>4, 8 cols (t&15)*8
        int rq = t >> 4, c8 = (t & 15) * 8;
        float4 v0 = make_float4(0.f, 0.f, 0.f, 0.f);
        float4 v1 = make_float4(0.f, 0.f, 0.f, 0.f);
        #pragma unroll
        for (int w = 0; w < 4; ++w) {
            const float* p = &scr[(w * 16 + rq) * D + c8];
            float4 x = *(const float4*)p;
            float4 y = *(const float4*)(p + 4);
            v0.x += x.x; v0.y += x.y; v0.z += x.z; v0.w += x.w;
            v1.x += y.x; v1.y += y.y; v1.z += y.z; v1.w += y.w;
        }
        *(float4*)&hw[(r0 + rq) * D + c8] = v0;
        *(float4*)&hw[(r0 + rq) * D + c8 + 4] = v1;
    }
}

// ---------------- K_C: per-row gather, ballot-fused dedup (1 row/wave) ------
__global__ __launch_bounds__(256) void k_row(const int2* __restrict__ bucket,
                                             const int* __restrict__ cnt,
                                             const float* __restrict__ hw,
                                             const float* __restrict__ S,
                                             float* __restrict__ out) {
    __shared__ int2 lb[4][CAP];        // 3KB: per-wave bucket stage
    int t = threadIdx.x;
    int wv = t >> 6, lane = t & 63;
    int row = blockIdx.x * 4 + wv;
    int deg = cnt[row];
    if (deg > CAP) deg = CAP;
    const int2* bk = bucket + row * CAP;
    int2 e0 = bk[lane];
    int2 e1 = (lane < CAP - 64) ? bk[64 + lane] : make_int2(-1, 0);
    int   d0 = (lane < deg)      ? e0.x : -1;
    float w0 = (lane < deg)      ? __int_as_float(e0.y) : 0.f;
    int   d1 = (64 + lane < deg) ? e1.x : -1;
    float w1 = (64 + lane < deg) ? __int_as_float(e1.y) : 0.f;
    lb[wv][lane] = make_int2(d0, __float_as_int(w0));
    if (lane < CAP - 64) lb[wv][64 + lane] = make_int2(d1, __float_as_int(w1));
    int n0 = deg < 64 ? deg : 64;
    float2 acc = make_float2(0.f, 0.f);
    float dex = 0.f;
    const int2* myb = lb[wv];
    for (int j = 0; j < n0; ++j) {
        int2 ew = myb[j];                              // ds_read_b64 broadcast
        int dj = ew.x;
        float wj = __int_as_float(ew.y);
        unsigned long long m = __ballot(d0 == dj);     // dedup: earlier slot match?
        if (m & ((1ull << j) - 1ull)) wj = 0.f;
        float2 hv = *(const float2*)&hw[dj * D + lane * 2];
        acc.x += wj * hv.x; acc.y += wj * hv.y;
        dex += wj;
    }
    for (int j = 64; j < deg; ++j) {
        int2 ew = myb[j];
        int dj = ew.x;
        float wj = __int_as_float(ew.y);
        unsigned long long m0 = __ballot(d0 == dj);
        unsigned long long m1 = __ballot(d1 == dj) & ((1ull << (j - 64)) - 1ull);
        if (m0 | m1) wj = 0.f;
        float2 hv = *(const float2*)&hw[dj * D + lane * 2];
        acc.x += wj * hv.x; acc.y += wj * hv.y;
        dex += wj;
    }
    float inv = 1.f / ((float)V + dex);
    float2 s = *(const float2*)&S[lane * 2];
    float2 o;
    o.x = (s.x + acc.x) * inv;
    o.y = (s.y + acc.y) * inv;
    *(float2*)&out[row * D + lane * 2] = o;
}

extern "C" void kernel_launch(void* const* d_in, const int* in_sizes, int n_in,
                              void* d_out, int out_size, void* d_ws, size_t ws_size,
                              hipStream_t stream) {
    const float* h   = (const float*)d_in[0];
    const int*   ei  = (const int*)d_in[1];
    const float* W   = (const float*)d_in[2];
    const float* att = (const float*)d_in[3];
    float* out = (float*)d_out;

    char* ws = (char*)d_ws;
    // workspace layout (bytes):
    //   hw     @ 0           4,194,304
    //   s1     @ 4,194,304      32,768
    //   s2     @ 4,227,072      32,768
    //   S      @ 4,259,840         512
    //   cnt    @ 4,260,352      32,768
    //   bucket @ 4,293,120   6,291,456   (8192 * 96 * 8B)
    //   Wt     @ 10,584,576     65,536
    //   Pc     @ 10,650,112    131,072   (256 blocks * 128 colsum partials)
    float* hw  = (float*)(ws);
    float* s1  = (float*)(ws + 4194304);
    float* s2  = (float*)(ws + 4227072);
    float* S   = (float*)(ws + 4259840);
    int*   cnt = (int*)(ws + 4260352);
    int2*  bucket = (int2*)(ws + 4293120);
    float* Wt  = (float*)(ws + 10584576);
    float* Pc  = (float*)(ws + 10650112);

    k_pre<<<256,  256, 0, stream>>>(h, W, att, Wt, s1, s2, Pc, cnt);
    k_mid<<<1537, 256, 0, stream>>>(h, Wt, W, ei, s1, s2, Pc, hw, S, cnt, bucket);
    k_row<<<2048, 256, 0, stream>>>(bucket, cnt, hw, S, out);
}

// Round 6
// 118.201 us; speedup vs baseline: 3.7276x; 1.1058x over previous
//
#include <hip/hip_runtime.h>
#include <hip/hip_bf16.h>
#include <math.h>

// GAT layer, V=8192, E=262144, D=128.
// out[i] = (S + sum_{distinct (i,j)} (exp(a_ij)-1)*hw[j]) / (V + sum (exp(a_ij)-1))
// a_ij = leakyrelu(s1[i]+s2[j], 0.2); s1/s2 = hw @ att halves; S = colsum(hw).
//
// R5 -> R6: R5's restructure regressed (131 vs R3's 119) -> revert to R3's
// proven 3-kernel shape; apply only traffic cuts: hw stored bf16 (gather
// 134->67MB), bucket entries packed to 4B (dst<<16|bf16(w)), cnt zeroed in
// k_hw prologue (memset node gone), S via plain-stored per-block partials Pb
// + one reducer block inside k_scatter (65K same-line atomics gone).

#define V 8192
#define E 262144
#define D 128
#define NEG_SLOPE 0.2f
#define CAP 96    // bucket capacity/row; max expected degree ~55 (11-sigma safe)

#define FMA4(acc, hv, wv) { acc.x += (hv)*(wv).x; acc.y += (hv)*(wv).y; \
                            acc.z += (hv)*(wv).z; acc.w += (hv)*(wv).w; }

__device__ __forceinline__ unsigned short f2bf(float f) {   // RNE fp32->bf16
    unsigned u = __float_as_uint(f);
    return (unsigned short)((u + 0x7fffu + ((u >> 16) & 1u)) >> 16);
}
__device__ __forceinline__ float bf2f_low(int p) {          // low 16 bits -> float
    return __uint_as_float(((unsigned)p) << 16);
}

// ---------------- K1: hw(bf16) = h @ W^T, fused s1/s2 + colsum partials ------
// 512 blocks x 256 thr, 16 rows/block; LDS-tiled W (R3-proven core).
__global__ __launch_bounds__(256) void k_hw(const float* __restrict__ h,
                                            const float* __restrict__ W,
                                            const float* __restrict__ att,
                                            unsigned short* __restrict__ hwb,
                                            float* __restrict__ s1,
                                            float* __restrict__ s2,
                                            float* __restrict__ Pb,
                                            int* __restrict__ cnt) {
    __shared__ float Wt[D * 132];      // W transposed, padded stride
    __shared__ float hs[16][D];        // h rows; reused as colsum scratch
    __shared__ float atts[2 * D];
    int t = threadIdx.x, b = blockIdx.x;
    int g0 = b * 256 + t;
    if (g0 < V) cnt[g0] = 0;           // zero cnt inline (kills memset dispatch)
    atts[t] = att[t];
    // stage W -> Wt (transposed): float4 global reads, 4 strided ds writes
    for (int f4 = t; f4 < (D * D) / 4; f4 += 256) {
        int o = f4 >> 5, k = (f4 * 4) & 127;
        float4 wv = *(const float4*)&W[o * D + k];
        Wt[(k + 0) * 132 + o] = wv.x;
        Wt[(k + 1) * 132 + o] = wv.y;
        Wt[(k + 2) * 132 + o] = wv.z;
        Wt[(k + 3) * 132 + o] = wv.w;
    }
    int r0 = b * 16;
    // stage 16 h rows: 2 float4 per thread
    {
        int row = t >> 5, col = (t * 4) & 127;
        *(float4*)&hs[row][col]     = *(const float4*)&h[(r0 + row) * D + col];
        *(float4*)&hs[row + 8][col] = *(const float4*)&h[(r0 + row + 8) * D + col];
    }
    __syncthreads();

    int c4 = (t & 31) * 4;   // 4-col group
    int rq = t >> 5;         // 0..7; this thread: rows rq and rq+8
    float4 acc0 = make_float4(0.f, 0.f, 0.f, 0.f);
    float4 acc1 = make_float4(0.f, 0.f, 0.f, 0.f);
    #pragma unroll 2
    for (int kq = 0; kq < D; kq += 4) {
        float4 ha = *(const float4*)&hs[rq][kq];
        float4 hb = *(const float4*)&hs[rq + 8][kq];
        float4 w0 = *(const float4*)&Wt[(kq + 0) * 132 + c4];
        float4 w1 = *(const float4*)&Wt[(kq + 1) * 132 + c4];
        float4 w2 = *(const float4*)&Wt[(kq + 2) * 132 + c4];
        float4 w3 = *(const float4*)&Wt[(kq + 3) * 132 + c4];
        FMA4(acc0, ha.x, w0); FMA4(acc0, ha.y, w1);
        FMA4(acc0, ha.z, w2); FMA4(acc0, ha.w, w3);
        FMA4(acc1, hb.x, w0); FMA4(acc1, hb.y, w1);
        FMA4(acc1, hb.z, w2); FMA4(acc1, hb.w, w3);
    }
    int rowa = r0 + rq, rowb = r0 + rq + 8;
    // store hw as bf16 (8B/thread/row, coalesced 256B per 32-lane group)
    ushort4 pa = make_ushort4(f2bf(acc0.x), f2bf(acc0.y), f2bf(acc0.z), f2bf(acc0.w));
    ushort4 pb = make_ushort4(f2bf(acc1.x), f2bf(acc1.y), f2bf(acc1.z), f2bf(acc1.w));
    *(ushort4*)&hwb[rowa * D + c4] = pa;
    *(ushort4*)&hwb[rowb * D + c4] = pb;

    // fused s1/s2 (fp32-exact, 32-lane group reduce)
    float p1a = acc0.x * atts[c4] + acc0.y * atts[c4 + 1] + acc0.z * atts[c4 + 2] + acc0.w * atts[c4 + 3];
    float p2a = acc0.x * atts[D + c4] + acc0.y * atts[D + c4 + 1] + acc0.z * atts[D + c4 + 2] + acc0.w * atts[D + c4 + 3];
    float p1b = acc1.x * atts[c4] + acc1.y * atts[c4 + 1] + acc1.z * atts[c4 + 2] + acc1.w * atts[c4 + 3];
    float p2b = acc1.x * atts[D + c4] + acc1.y * atts[D + c4 + 1] + acc1.z * atts[D + c4 + 2] + acc1.w * atts[D + c4 + 3];
    #pragma unroll
    for (int m = 16; m; m >>= 1) {
        p1a += __shfl_xor(p1a, m); p2a += __shfl_xor(p2a, m);
        p1b += __shfl_xor(p1b, m); p2b += __shfl_xor(p2b, m);
    }
    if ((t & 31) == 0) {
        s1[rowa] = p1a; s2[rowa] = p2a;
        s1[rowb] = p1b; s2[rowb] = p2b;
    }

    // colsum partial (fp32): 2-row sums -> LDS -> plain store Pb[b][col]
    __syncthreads();
    float* scr = &hs[0][0];
    scr[rq * D + c4 + 0] = acc0.x + acc1.x;
    scr[rq * D + c4 + 1] = acc0.y + acc1.y;
    scr[rq * D + c4 + 2] = acc0.z + acc1.z;
    scr[rq * D + c4 + 3] = acc0.w + acc1.w;
    __syncthreads();
    if (t < D) {
        float s = 0.f;
        #pragma unroll
        for (int r = 0; r < 8; ++r) s += scr[r * D + t];
        Pb[b * D + t] = s;              // no atomics
    }
}

// ---------------- K2: scatter (b<256, 4 edges/thr) | S-reduce (b==256) ------
__global__ __launch_bounds__(256) void k_scatter(const int* __restrict__ ei,
                                                 const float* __restrict__ s1,
                                                 const float* __restrict__ s2,
                                                 int* __restrict__ cnt,
                                                 int* __restrict__ bucket,
                                                 const float* __restrict__ Pb,
                                                 float* __restrict__ S) {
    int b = blockIdx.x, t = threadIdx.x;
    if (b < 256) {
        int g = b * 256 + t;
        int4 sv = *(const int4*)&ei[4 * g];
        int4 dv = *(const int4*)&ei[E + 4 * g];
        const int* sp = &sv.x;
        const int* dp = &dv.x;
        #pragma unroll
        for (int j = 0; j < 4; ++j) {
            int src = sp[j], dst = dp[j];
            float a = s1[src] + s2[dst];
            a = a > 0.f ? a : NEG_SLOPE * a;
            float w = expf(a) - 1.f;
            int pos = atomicAdd(&cnt[src], 1);
            if (pos < CAP)
                bucket[src * CAP + pos] = (dst << 16) | (int)f2bf(w);  // 4B packed
        }
    } else {
        // S = reduce of 512 colsum partials (runs parallel with scatter blocks)
        __shared__ float red[256];
        int c = t & 127, half = t >> 7;
        float s = 0.f;
        #pragma unroll 4
        for (int r = half; r < 512; r += 2)
            s += Pb[r * D + c];         // 2 coalesced 512B rows per step
        red[t] = s;
        __syncthreads();
        if (t < D) S[t] = red[t] + red[D + t];
    }
}

// ---------------- K3: per-row gather, shfl-broadcast + ballot dedup ----------
// 2048 blocks x 256 thr, 1 row/wave. Gathers bf16 hw (256B/entry).
__global__ __launch_bounds__(256) void k_row(const int* __restrict__ bucket,
                                             const int* __restrict__ cnt,
                                             const unsigned short* __restrict__ hwb,
                                             const float* __restrict__ S,
                                             float* __restrict__ out) {
    int t = threadIdx.x;
    int wv = t >> 6, lane = t & 63;
    int row = blockIdx.x * 4 + wv;
    int deg = cnt[row];
    if (deg > CAP) deg = CAP;
    const int* bk = bucket + row * CAP;
    int e0 = bk[lane];                              // slots 0..63
    int e1 = (lane < CAP - 64) ? bk[64 + lane] : 0; // slots 64..95
    int p0 = (lane < deg)      ? e0 : (int)0xFFFF0000;  // invalid: d=-1, w=0
    int p1 = (64 + lane < deg) ? e1 : (int)0xFFFF0000;
    int d0 = p0 >> 16;
    int d1 = p1 >> 16;
    int n0 = deg < 64 ? deg : 64;
    float2 acc = make_float2(0.f, 0.f);
    float dex = 0.f;
    for (int j = 0; j < n0; ++j) {
        int pj = __shfl(p0, j);                     // one shfl: dst+weight packed
        int dj = pj >> 16;
        float wj = bf2f_low(pj);
        unsigned long long m = __ballot(d0 == dj);  // earlier slot has same dst?
        if (m & ((1ull << j) - 1ull)) wj = 0.f;
        unsigned hv = *(const unsigned*)&hwb[dj * D + lane * 2];  // 2 bf16, 256B/wave
        acc.x += wj * __uint_as_float(hv << 16);
        acc.y += wj * __uint_as_float(hv & 0xFFFF0000u);
        dex += wj;
    }
    for (int j = 64; j < deg; ++j) {
        int pj = __shfl(p1, j - 64);
        int dj = pj >> 16;
        float wj = bf2f_low(pj);
        unsigned long long m0 = __ballot(d0 == dj);
        unsigned long long m1 = __ballot(d1 == dj) & ((1ull << (j - 64)) - 1ull);
        if (m0 | m1) wj = 0.f;
        unsigned hv = *(const unsigned*)&hwb[dj * D + lane * 2];
        acc.x += wj * __uint_as_float(hv << 16);
        acc.y += wj * __uint_as_float(hv & 0xFFFF0000u);
        dex += wj;
    }
    float inv = 1.f / ((float)V + dex);
    float2 s = *(const float2*)&S[lane * 2];
    float2 o;
    o.x = (s.x + acc.x) * inv;
    o.y = (s.y + acc.y) * inv;
    *(float2*)&out[row * D + lane * 2] = o;
}

extern "C" void kernel_launch(void* const* d_in, const int* in_sizes, int n_in,
                              void* d_out, int out_size, void* d_ws, size_t ws_size,
                              hipStream_t stream) {
    const float* h   = (const float*)d_in[0];
    const int*   ei  = (const int*)d_in[1];
    const float* W   = (const float*)d_in[2];
    const float* att = (const float*)d_in[3];
    float* out = (float*)d_out;

    char* ws = (char*)d_ws;
    // workspace layout (bytes):
    //   hwb    @ 0          2,097,152   (bf16 hw)
    //   s1     @ 2,097,152     32,768
    //   s2     @ 2,129,920     32,768
    //   S      @ 2,162,688        512
    //   cnt    @ 2,163,200     32,768
    //   bucket @ 2,195,968   3,145,728  (8192 * 96 * 4B packed)
    //   Pb     @ 5,341,696     262,144  (512 blocks * 128 colsum partials)
    unsigned short* hwb = (unsigned short*)(ws);
    float* s1  = (float*)(ws + 2097152);
    float* s2  = (float*)(ws + 2129920);
    float* S   = (float*)(ws + 2162688);
    int*   cnt = (int*)(ws + 2163200);
    int*   bucket = (int*)(ws + 2195968);
    float* Pb  = (float*)(ws + 5341696);

    k_hw     <<<512,  256, 0, stream>>>(h, W, att, hwb, s1, s2, Pb, cnt);
    k_scatter<<<257,  256, 0, stream>>>(ei, s1, s2, cnt, bucket, Pb, S);
    k_row    <<<2048, 256, 0, stream>>>(bucket, cnt, hwb, S, out);
}

// Round 7
// 106.002 us; speedup vs baseline: 4.1566x; 1.1151x over previous
//
#include <hip/hip_runtime.h>
#include <hip/hip_bf16.h>
#include <math.h>

// GAT layer, V=8192, E=262144, D=128.
// out[i] = (S + sum_{distinct (i,j)} (exp(a_ij)-1)*hw[j]) / (V + sum (exp(a_ij)-1))
// a_ij = leakyrelu(s1[i]+s2[j], 0.2); s1/s2 = hw @ att halves; S = colsum(hw).
//
// R6 -> R7: traffic cuts were neutral => kernels are latency-chain-bound, not
// byte-bound (R4 datum: invariant overhead ~61us, kernels ~57us). This round
// shortens serial chains: k_row processes 4 entries/iter (1 ds_read_b128
// broadcast + 4 gathers in flight), k_scatter 1 edge/thread at 4 waves/SIMD
// (one atomic, not 4 serial), k_hw 4 rows/thread (half the LDS ops per FMA,
// h via global broadcast). Numerics identical to R6 (absmax 2.4e-4).

#define V 8192
#define E 262144
#define D 128
#define NEG_SLOPE 0.2f
#define CAP 96    // bucket capacity/row; max expected degree ~55 (11-sigma safe)

#define FMA4(acc, hv, wv) { acc.x += (hv)*(wv).x; acc.y += (hv)*(wv).y; \
                            acc.z += (hv)*(wv).z; acc.w += (hv)*(wv).w; }

__device__ __forceinline__ unsigned short f2bf(float f) {   // RNE fp32->bf16
    unsigned u = __float_as_uint(f);
    return (unsigned short)((u + 0x7fffu + ((u >> 16) & 1u)) >> 16);
}
__device__ __forceinline__ float bf2f_low(int p) {          // low 16 bits -> float
    return __uint_as_float(((unsigned)p) << 16);
}

// ---------------- K1: hw(bf16) = h @ W^T, fused s1/s2 + colsum partials ------
// 256 blocks x 256 thr, 32 rows/block, 4 rows/thread. LDS = Wt only (67.6KB).
__global__ __launch_bounds__(256) void k_hw(const float* __restrict__ h,
                                            const float* __restrict__ W,
                                            const float* __restrict__ att,
                                            unsigned short* __restrict__ hwb,
                                            float* __restrict__ s1,
                                            float* __restrict__ s2,
                                            float* __restrict__ Pb,
                                            int* __restrict__ cnt) {
    __shared__ float Wt[D * 132];      // W transposed, pad 132 breaks write conflicts
    __shared__ float atts[2 * D];
    __shared__ float scr[8 * D];       // colsum scratch
    int t = threadIdx.x, b = blockIdx.x;
    if (b < 32) cnt[b * 256 + t] = 0;  // zero cnt inline (no memset dispatch)
    atts[t] = att[t];
    for (int f4 = t; f4 < (D * D) / 4; f4 += 256) {
        int o = f4 >> 5, k = (f4 & 31) * 4;
        float4 wv = *(const float4*)&W[o * D + k];   // coalesced 16B/lane
        Wt[(k + 0) * 132 + o] = wv.x;
        Wt[(k + 1) * 132 + o] = wv.y;
        Wt[(k + 2) * 132 + o] = wv.z;
        Wt[(k + 3) * 132 + o] = wv.w;
    }
    __syncthreads();

    int c4 = (t & 31) * 4;   // 4-col group
    int rq = t >> 5;         // 0..7; this thread: rows rq, rq+8, rq+16, rq+24
    int r0 = b * 32;
    float4 a0 = make_float4(0.f,0.f,0.f,0.f), a1 = a0, a2 = a0, a3 = a0;
    const float* h0p = &h[(r0 + rq     ) * D];
    const float* h1p = &h[(r0 + rq +  8) * D];
    const float* h2p = &h[(r0 + rq + 16) * D];
    const float* h3p = &h[(r0 + rq + 24) * D];
    #pragma unroll 4
    for (int kq = 0; kq < D; kq += 4) {
        float4 w0 = *(const float4*)&Wt[(kq + 0) * 132 + c4];
        float4 w1 = *(const float4*)&Wt[(kq + 1) * 132 + c4];
        float4 w2 = *(const float4*)&Wt[(kq + 2) * 132 + c4];
        float4 w3 = *(const float4*)&Wt[(kq + 3) * 132 + c4];
        float4 hv;
        hv = *(const float4*)&h0p[kq];   // wave-broadcast 16B (L1 after 1st use)
        FMA4(a0, hv.x, w0); FMA4(a0, hv.y, w1); FMA4(a0, hv.z, w2); FMA4(a0, hv.w, w3);
        hv = *(const float4*)&h1p[kq];
        FMA4(a1, hv.x, w0); FMA4(a1, hv.y, w1); FMA4(a1, hv.z, w2); FMA4(a1, hv.w, w3);
        hv = *(const float4*)&h2p[kq];
        FMA4(a2, hv.x, w0); FMA4(a2, hv.y, w1); FMA4(a2, hv.z, w2); FMA4(a2, hv.w, w3);
        hv = *(const float4*)&h3p[kq];
        FMA4(a3, hv.x, w0); FMA4(a3, hv.y, w1); FMA4(a3, hv.z, w2); FMA4(a3, hv.w, w3);
    }
    // store hw rows as bf16
    *(ushort4*)&hwb[(r0 + rq     ) * D + c4] = make_ushort4(f2bf(a0.x), f2bf(a0.y), f2bf(a0.z), f2bf(a0.w));
    *(ushort4*)&hwb[(r0 + rq +  8) * D + c4] = make_ushort4(f2bf(a1.x), f2bf(a1.y), f2bf(a1.z), f2bf(a1.w));
    *(ushort4*)&hwb[(r0 + rq + 16) * D + c4] = make_ushort4(f2bf(a2.x), f2bf(a2.y), f2bf(a2.z), f2bf(a2.w));
    *(ushort4*)&hwb[(r0 + rq + 24) * D + c4] = make_ushort4(f2bf(a3.x), f2bf(a3.y), f2bf(a3.z), f2bf(a3.w));

    // fused s1/s2 (fp32, 32-lane group reduce), 4 rows
    float q1[4], q2[4];
    float4* accs[4] = {&a0, &a1, &a2, &a3};
    #pragma unroll
    for (int r = 0; r < 4; ++r) {
        float4 v = *accs[r];
        q1[r] = v.x * atts[c4] + v.y * atts[c4 + 1] + v.z * atts[c4 + 2] + v.w * atts[c4 + 3];
        q2[r] = v.x * atts[D + c4] + v.y * atts[D + c4 + 1] + v.z * atts[D + c4 + 2] + v.w * atts[D + c4 + 3];
    }
    #pragma unroll
    for (int m = 16; m; m >>= 1) {
        #pragma unroll
        for (int r = 0; r < 4; ++r) {
            q1[r] += __shfl_xor(q1[r], m);
            q2[r] += __shfl_xor(q2[r], m);
        }
    }
    if ((t & 31) == 0) {
        #pragma unroll
        for (int r = 0; r < 4; ++r) {
            s1[r0 + rq + r * 8] = q1[r];
            s2[r0 + rq + r * 8] = q2[r];
        }
    }

    // colsum partial: 4-row sums -> LDS -> plain store Pb[b][col] (no atomics)
    scr[rq * D + c4 + 0] = a0.x + a1.x + a2.x + a3.x;
    scr[rq * D + c4 + 1] = a0.y + a1.y + a2.y + a3.y;
    scr[rq * D + c4 + 2] = a0.z + a1.z + a2.z + a3.z;
    scr[rq * D + c4 + 3] = a0.w + a1.w + a2.w + a3.w;
    __syncthreads();
    if (t < D) {
        float s = 0.f;
        #pragma unroll
        for (int r = 0; r < 8; ++r) s += scr[r * D + t];
        Pb[b * D + t] = s;
    }
}

// ---------------- K2: scatter (b<1024, 1 edge/thr) | S-reduce (b==1024) -----
__global__ __launch_bounds__(256) void k_scatter(const int* __restrict__ ei,
                                                 const float* __restrict__ s1,
                                                 const float* __restrict__ s2,
                                                 int* __restrict__ cnt,
                                                 int* __restrict__ bucket,
                                                 const float* __restrict__ Pb,
                                                 float* __restrict__ S) {
    int b = blockIdx.x, t = threadIdx.x;
    if (b < 1024) {
        int g = b * 256 + t;               // one edge/thread: single atomic chain
        int src = ei[g];
        int dst = ei[E + g];
        float a = s1[src] + s2[dst];
        a = a > 0.f ? a : NEG_SLOPE * a;
        float w = expf(a) - 1.f;
        int pos = atomicAdd(&cnt[src], 1);
        if (pos < CAP)
            bucket[src * CAP + pos] = (dst << 16) | (int)f2bf(w);  // 4B packed
    } else {
        __shared__ float red[256];
        int c = t & 127, half = t >> 7;
        float s = 0.f;
        #pragma unroll 4
        for (int r = half; r < 256; r += 2)
            s += Pb[r * D + c];
        red[t] = s;
        __syncthreads();
        if (t < D) S[t] = red[t] + red[D + t];
    }
}

// ---------------- K3: per-row gather, 4 entries/iter, ballot dedup -----------
// 2048 blocks x 256 thr, 1 row/wave. LDS-staged bucket, ds_read_b128 broadcast.
__global__ __launch_bounds__(256) void k_row(const int* __restrict__ bucket,
                                             const int* __restrict__ cnt,
                                             const unsigned short* __restrict__ hwb,
                                             const float* __restrict__ S,
                                             float* __restrict__ out) {
    __shared__ int lb[4][CAP];             // 1.5KB, 16B-aligned per wave
    int t = threadIdx.x;
    int wv = t >> 6, lane = t & 63;
    int row = blockIdx.x * 4 + wv;
    int deg = cnt[row];
    if (deg > CAP) deg = CAP;
    const int* bk = bucket + row * CAP;
    int e0 = bk[lane];
    int e1 = (lane < CAP - 64) ? bk[64 + lane] : 0;
    int p0 = (lane < deg)      ? e0 : (int)0xFFFF0000;   // invalid: d=-1, w=0
    int p1 = (64 + lane < deg) ? e1 : (int)0xFFFF0000;
    lb[wv][lane] = p0;
    if (lane < CAP - 64) lb[wv][64 + lane] = p1;
    int d0 = p0 >> 16;                      // arithmetic: invalid -> -1
    int d1 = p1 >> 16;
    // wave-private LDS (self-written): no barrier needed, compiler emits lgkmcnt
    int n0 = deg < 64 ? deg : 64;
    float accx = 0.f, accy = 0.f, dex = 0.f;
    const int* myb = lb[wv];
    int col2 = lane * 2;
    int j = 0;
    for (; j + 4 <= n0; j += 4) {
        int4 pq = *(const int4*)&myb[j];    // ds_read_b128 broadcast: 4 entries
        int dj0 = pq.x >> 16, dj1 = pq.y >> 16, dj2 = pq.z >> 16, dj3 = pq.w >> 16;
        unsigned hv0 = *(const unsigned*)&hwb[dj0 * D + col2];   // 4 gathers in flight
        unsigned hv1 = *(const unsigned*)&hwb[dj1 * D + col2];
        unsigned hv2 = *(const unsigned*)&hwb[dj2 * D + col2];
        unsigned hv3 = *(const unsigned*)&hwb[dj3 * D + col2];
        unsigned long long m0 = __ballot(d0 == dj0);
        unsigned long long m1 = __ballot(d0 == dj1);
        unsigned long long m2 = __ballot(d0 == dj2);
        unsigned long long m3 = __ballot(d0 == dj3);
        float w0 = (m0 & ((1ull << (j + 0)) - 1ull)) ? 0.f : bf2f_low(pq.x);
        float w1 = (m1 & ((1ull << (j + 1)) - 1ull)) ? 0.f : bf2f_low(pq.y);
        float w2 = (m2 & ((1ull << (j + 2)) - 1ull)) ? 0.f : bf2f_low(pq.z);
        float w3 = (m3 & ((1ull << (j + 3)) - 1ull)) ? 0.f : bf2f_low(pq.w);
        accx += w0 * __uint_as_float(hv0 << 16);
        accy += w0 * __uint_as_float(hv0 & 0xFFFF0000u);
        accx += w1 * __uint_as_float(hv1 << 16);
        accy += w1 * __uint_as_float(hv1 & 0xFFFF0000u);
        accx += w2 * __uint_as_float(hv2 << 16);
        accy += w2 * __uint_as_float(hv2 & 0xFFFF0000u);
        accx += w3 * __uint_as_float(hv3 << 16);
        accy += w3 * __uint_as_float(hv3 & 0xFFFF0000u);
        dex += w0 + w1 + w2 + w3;
    }
    for (; j < n0; ++j) {                   // tail (<4 entries)
        int pj = myb[j];
        int dj = pj >> 16;
        float wj = bf2f_low(pj);
        unsigned long long m = __ballot(d0 == dj);
        if (m & ((1ull << j) - 1ull)) wj = 0.f;
        unsigned hv = *(const unsigned*)&hwb[dj * D + col2];
        accx += wj * __uint_as_float(hv << 16);
        accy += wj * __uint_as_float(hv & 0xFFFF0000u);
        dex += wj;
    }
    for (j = 64; j < deg; ++j) {            // slots 64..95 (rare: deg>64)
        int pj = myb[j];
        int dj = pj >> 16;
        float wj = bf2f_low(pj);
        unsigned long long m0 = __ballot(d0 == dj);
        unsigned long long m1 = __ballot(d1 == dj) & ((1ull << (j - 64)) - 1ull);
        if (m0 | m1) wj = 0.f;
        unsigned hv = *(const unsigned*)&hwb[dj * D + col2];
        accx += wj * __uint_as_float(hv << 16);
        accy += wj * __uint_as_float(hv & 0xFFFF0000u);
        dex += wj;
    }
    float inv = 1.f / ((float)V + dex);
    float2 s = *(const float2*)&S[col2];
    float2 o;
    o.x = (s.x + accx) * inv;
    o.y = (s.y + accy) * inv;
    *(float2*)&out[row * D + col2] = o;
}

extern "C" void kernel_launch(void* const* d_in, const int* in_sizes, int n_in,
                              void* d_out, int out_size, void* d_ws, size_t ws_size,
                              hipStream_t stream) {
    const float* h   = (const float*)d_in[0];
    const int*   ei  = (const int*)d_in[1];
    const float* W   = (const float*)d_in[2];
    const float* att = (const float*)d_in[3];
    float* out = (float*)d_out;

    char* ws = (char*)d_ws;
    // workspace layout (bytes):
    //   hwb    @ 0          2,097,152   (bf16 hw)
    //   s1     @ 2,097,152     32,768
    //   s2     @ 2,129,920     32,768
    //   S      @ 2,162,688        512
    //   cnt    @ 2,163,200     32,768
    //   bucket @ 2,195,968   3,145,728  (8192 * 96 * 4B packed)
    //   Pb     @ 5,341,696     131,072  (256 blocks * 128 colsum partials)
    unsigned short* hwb = (unsigned short*)(ws);
    float* s1  = (float*)(ws + 2097152);
    float* s2  = (float*)(ws + 2129920);
    float* S   = (float*)(ws + 2162688);
    int*   cnt = (int*)(ws + 2163200);
    int*   bucket = (int*)(ws + 2195968);
    float* Pb  = (float*)(ws + 5341696);

    k_hw     <<<256,  256, 0, stream>>>(h, W, att, hwb, s1, s2, Pb, cnt);
    k_scatter<<<1025, 256, 0, stream>>>(ei, s1, s2, cnt, bucket, Pb, S);
    k_row    <<<2048, 256, 0, stream>>>(bucket, cnt, hwb, S, out);
}